// Round 3
// baseline (378.817 us; speedup 1.0000x reference)
//
#include <hip/hip_runtime.h>
#include <hip/hip_bf16.h>
#include <stdint.h>

#define DEVINL __device__ __forceinline__

typedef unsigned short u16;
typedef __attribute__((ext_vector_type(8))) short bf16x8;    // 8 bf16 = 4 VGPRs (MFMA A/B frag)
typedef __attribute__((ext_vector_type(16))) float f32x16;   // 32x32 MFMA C/D frag
typedef __attribute__((ext_vector_type(8))) unsigned short u16x8;

DEVINL u16 f2bf(float f) {               // round-to-nearest-even f32 -> bf16
  union { float f; unsigned u; } x; x.f = f;
  unsigned r = x.u + 0x7fffu + ((x.u >> 16) & 1u);
  return (u16)(r >> 16);
}
DEVINL float bf2f(u16 u) {
  union { float f; unsigned u; } x; x.u = ((unsigned)u) << 16; return x.f;
}

DEVINL void load_lds16(const u16* g, u16* l) {
  // async global->LDS, 16B per lane; LDS dest = wave-uniform base + lane*16
  __builtin_amdgcn_global_load_lds(
      (const __attribute__((address_space(1))) void*)g,
      (__attribute__((address_space(3))) void*)l, 16, 0, 0);
}

// ---------------------------------------------------------------------------
// C[M,N] = A[M,K] @ Bt[N,K]^T * scale (+ bias)    A,Bt bf16; C bf16 or f32
// A row stride = lda, Bt row stride = ldb, C row stride = N.
// BIAS_MODE: 0 none, 1 bias[col], 2 bias[row], 3 dual col bias split at N/2
// 256x256 tile, BK=32, ring-4 LDS slots, counted-vmcnt pipeline (depth 3),
// 32x32x16 MFMA, XCD-chunked block swizzle (requires gridDim.x*gridDim.y % 8 == 0).
// 512 threads = 8 waves (2M x 4N), wave tile 128x64 -> acc[4][2] of f32x16.
//
// Race-freedom (unchanged from round 2): iteration t reads slot t&3 after
// {vmcnt(8); s_barrier}; stage(t+3) -> slot (t-1)&3 whose readers all passed
// this barrier. One barrier per K-step; vmcnt never drains mid-loop.
// LDS swizzle: 16B-block blk' = blk ^ ((row>>1)&3), applied on the GLOBAL
// source (global_load_lds writes linearly) and on the ds_read address.
// ---------------------------------------------------------------------------
template<bool OUT_F32, int BIAS_MODE>
__global__ __launch_bounds__(512)
void gemm256(const u16* __restrict__ A, const u16* __restrict__ Bt,
             void* __restrict__ Cv,
             const float* __restrict__ bias, const float* __restrict__ bias2,
             int M, int N, int K, int lda, int ldb, float scale,
             long sA, long sB, long sC)
{
  const int bz = blockIdx.z;
  A  += (size_t)bz * sA;
  Bt += (size_t)bz * sB;

  // XCD-aware chunked swizzle within the z-slice (bijective: nb % 8 == 0)
  const int gx = gridDim.x;
  {
  }
  int id = blockIdx.x + gx * blockIdx.y;
  const int nb = gx * gridDim.y;
  const int q  = nb >> 3;
  id = (id & 7) * q + (id >> 3);
  const int bxs = id % gx, bys = id / gx;

  const int tid  = threadIdx.x;
  const int lane = tid & 63;
  const int w    = tid >> 6;
  const int wm   = w >> 2;          // 0..1  (M direction, 128 rows each)
  const int wn   = w & 3;           // 0..3  (N direction, 64 cols each)
  const int brow = bys * 256;
  const int bcol = bxs * 256;

  __shared__ u16 lds[4][2][256 * 32];   // [slot][A/B][row*32+col]  128 KiB

  const u16* gA = A  + (size_t)brow * lda;
  const u16* gB = Bt + (size_t)bcol * ldb;

  // per-thread staging descriptors: 2 rounds x (A,B); 16B chunk c = r*512+tid
  int c8[2], soffA[2], soffB[2];
#pragma unroll
  for (int r = 0; r < 2; ++r) {
    const int c    = r * 512 + tid;
    const int row  = c >> 2;
    const int blk  = c & 3;
    const int sblk = blk ^ ((row >> 1) & 3);   // inverse swizzle on source
    c8[r]    = c * 8;
    soffA[r] = row * lda + sblk * 8;
    soffB[r] = row * ldb + sblk * 8;
  }
  const int NT = K >> 5;

  f32x16 acc[4][2] = {};

  // prologue: stage tiles 0..2
#pragma unroll
  for (int tt = 0; tt < 3; ++tt) {
    const int kt = tt * 32;
#pragma unroll
    for (int r = 0; r < 2; ++r) load_lds16(gA + soffA[r] + kt, &lds[tt][0][c8[r]]);
#pragma unroll
    for (int r = 0; r < 2; ++r) load_lds16(gB + soffB[r] + kt, &lds[tt][1][c8[r]]);
  }
  __builtin_amdgcn_sched_barrier(0);

  // ds_read addressing: frag row/col = base + (lane&31); k-half = lane>>5.
  // b128 at elem [row*32 + ((s*2 + kh) ^ ((row>>1)&3))*8], s = K=16 slice.
  const int l31 = lane & 31, kh = lane >> 5;
  int rA32[4], smA[4], rB32[2], smB[2];
#pragma unroll
  for (int m = 0; m < 4; ++m) {
    const int row = wm * 128 + m * 32 + l31;
    rA32[m] = row * 32; smA[m] = (row >> 1) & 3;
  }
#pragma unroll
  for (int n = 0; n < 2; ++n) {
    const int row = wn * 64 + n * 32 + l31;
    rB32[n] = row * 32; smB[n] = (row >> 1) & 3;
  }

  for (int t = 0; t < NT; ++t) {
    if (t < NT - 2)       asm volatile("s_waitcnt vmcnt(8)" ::: "memory");
    else if (t == NT - 2) asm volatile("s_waitcnt vmcnt(4)" ::: "memory");
    else                  asm volatile("s_waitcnt vmcnt(0)" ::: "memory");
    __builtin_amdgcn_s_barrier();
    __builtin_amdgcn_sched_barrier(0);

    const u16* la = lds[t & 3][0];
    const u16* lb = lds[t & 3][1];
    bf16x8 av[2][4], bv[2][2];
#pragma unroll
    for (int s = 0; s < 2; ++s) {
#pragma unroll
      for (int m = 0; m < 4; ++m)
        av[s][m] = *(const bf16x8*)&la[rA32[m] + (((s * 2 + kh) ^ smA[m]) << 3)];
#pragma unroll
      for (int n = 0; n < 2; ++n)
        bv[s][n] = *(const bf16x8*)&lb[rB32[n] + (((s * 2 + kh) ^ smB[n]) << 3)];
    }

    if (t + 3 < NT) {                      // stage tile t+3 into slot (t-1)&3
      const int kt = (t + 3) * 32, sl = (t + 3) & 3;
#pragma unroll
      for (int r = 0; r < 2; ++r) load_lds16(gA + soffA[r] + kt, &lds[sl][0][c8[r]]);
#pragma unroll
      for (int r = 0; r < 2; ++r) load_lds16(gB + soffB[r] + kt, &lds[sl][1][c8[r]]);
    }

    __builtin_amdgcn_s_setprio(1);
#pragma unroll
    for (int s = 0; s < 2; ++s)
#pragma unroll
      for (int m = 0; m < 4; ++m)
#pragma unroll
        for (int n = 0; n < 2; ++n)
          acc[m][n] = __builtin_amdgcn_mfma_f32_32x32x16_bf16(av[s][m], bv[s][n], acc[m][n], 0, 0, 0);
    __builtin_amdgcn_s_setprio(0);
  }

  // epilogue: 32x32 C/D layout: col = lane&31, row = (reg&3)+8*(reg>>2)+4*(lane>>5)
  float* Cf = (float*)Cv + (size_t)bz * sC;
  u16*   Cb = (u16*)Cv   + (size_t)bz * sC;
  const int colb = bcol + wn * 64 + l31;
  const int rowb = brow + wm * 128 + 4 * kh;
#pragma unroll
  for (int m = 0; m < 4; ++m) {
    const int r0 = rowb + m * 32;
#pragma unroll
    for (int n = 0; n < 2; ++n) {
      const int col = colb + n * 32;
      float badd = 0.f;
      if (BIAS_MODE == 1) badd = bias[col];
      if (BIAS_MODE == 3) badd = (col < (N >> 1)) ? bias[col] : bias2[col - (N >> 1)];
#pragma unroll
      for (int r = 0; r < 16; ++r) {
        const int row = r0 + (r & 3) + ((r >> 2) << 3);
        float v = acc[m][n][r] * scale + badd;
        if (BIAS_MODE == 2) v += bias[row];
        if (OUT_F32) Cf[(size_t)row * N + col] = v;
        else         Cb[(size_t)row * N + col] = f2bf(v);
      }
    }
  }
}

// ---------------------------------------------------------------------------
__global__ __launch_bounds__(256)
void cvt_f32_bf16(const float* __restrict__ in, u16* __restrict__ out, int n8)
{
  const int i = blockIdx.x * 256 + threadIdx.x;
  if (i >= n8) return;
  const float4* in4 = (const float4*)in;
  float4 a = in4[2 * i], b = in4[2 * i + 1];
  u16x8 o;
  o[0] = f2bf(a.x); o[1] = f2bf(a.y); o[2] = f2bf(a.z); o[3] = f2bf(a.w);
  o[4] = f2bf(b.x); o[5] = f2bf(b.y); o[6] = f2bf(b.z); o[7] = f2bf(b.w);
  ((u16x8*)out)[i] = o;
}

// transpose + convert 1024x1024 fp32 -> bf16 (Wt[e][d] = W[d][e]), z picks weight
__global__ __launch_bounds__(256)
void transpose_cvt(const float* __restrict__ W0, const float* __restrict__ W1,
                   const float* __restrict__ W2, const float* __restrict__ W3,
                   u16* __restrict__ T0, u16* __restrict__ T1,
                   u16* __restrict__ T2, u16* __restrict__ T3)
{
  const float* W = blockIdx.z == 0 ? W0 : blockIdx.z == 1 ? W1 : blockIdx.z == 2 ? W2 : W3;
  u16*         T = blockIdx.z == 0 ? T0 : blockIdx.z == 1 ? T1 : blockIdx.z == 2 ? T2 : T3;
  __shared__ float tile[32][33];
  const int d0 = blockIdx.y * 32, e0 = blockIdx.x * 32;
  const int tx = threadIdx.x, ty = threadIdx.y;
#pragma unroll
  for (int r = ty; r < 32; r += 8)
    tile[r][tx] = W[(size_t)(d0 + r) * 1024 + e0 + tx];
  __syncthreads();
#pragma unroll
  for (int r = ty; r < 32; r += 8)
    T[(size_t)(e0 + r) * 1024 + d0 + tx] = f2bf(tile[tx][r]);
}

// row softmax in place over bf16 rows of length 2048 (one block per row)
__global__ __launch_bounds__(256)
void softmax_rows(u16* __restrict__ S)
{
  u16* p = S + (size_t)blockIdx.x * 2048;
  const int tid = threadIdx.x;
  const int w = tid >> 6, lane = tid & 63;

  u16x8 v = ((const u16x8*)p)[tid];
  float f[8];
  float m = -1e30f;
#pragma unroll
  for (int j = 0; j < 8; ++j) { f[j] = bf2f(v[j]); m = fmaxf(m, f[j]); }
#pragma unroll
  for (int o = 32; o; o >>= 1) m = fmaxf(m, __shfl_xor(m, o));

  __shared__ float red[8];
  if (lane == 0) red[w] = m;
  __syncthreads();
  m = fmaxf(fmaxf(red[0], red[1]), fmaxf(red[2], red[3]));

  float s = 0.f;
#pragma unroll
  for (int j = 0; j < 8; ++j) { f[j] = __expf(f[j] - m); s += f[j]; }
#pragma unroll
  for (int o = 32; o; o >>= 1) s += __shfl_xor(s, o);
  if (lane == 0) red[4 + w] = s;
  __syncthreads();
  s = red[4] + red[5] + red[6] + red[7];
  const float inv = 1.f / s;

  u16x8 o8;
#pragma unroll
  for (int j = 0; j < 8; ++j) o8[j] = f2bf(f[j] * inv);
  ((u16x8*)p)[tid] = o8;
}

// ---------------------------------------------------------------------------
extern "C" void kernel_launch(void* const* d_in, const int* in_sizes, int n_in,
                              void* d_out, int out_size, void* d_ws, size_t ws_size,
                              hipStream_t stream)
{
  const float* X  = (const float*)d_in[0];
  const float* Wq = (const float*)d_in[1];
  const float* bq = (const float*)d_in[2];
  const float* Wk = (const float*)d_in[3];
  const float* bk = (const float*)d_in[4];
  const float* Wv = (const float*)d_in[5];
  const float* bv = (const float*)d_in[6];
  const float* Wo = (const float*)d_in[7];
  const float* bo = (const float*)d_in[8];

  constexpr int B = 8, N = 2048, D = 1024;
  constexpr size_t TOK = (size_t)B * N;        // 16384
  constexpr size_t SZX = TOK * D;              // 16,777,216 elems
  constexpr size_t SZW = (size_t)D * D;

  if (ws_size < (4 * SZX + 4 * SZW) * sizeof(u16)) return;  // ~143 MB needed

  u16* Xb  = (u16*)d_ws;        // X bf16; later reused as attn_out (AO)
  u16* Wqt = Xb  + SZX;         // Wq^T  — Wqt/Wkt contiguous => stacked QK weight
  u16* Wkt = Wqt + SZW;
  u16* Wvt = Wkt + SZW;
  u16* Wot = Wvt + SZW;
  u16* QK  = Wot + SZW;         // fused [16384][2048]: cols 0..1023 Q, 1024..2047 K
  u16* Vt  = QK  + 2 * SZX;     // [B][D][N] (V transposed per batch)
  u16* S   = (u16*)d_out;       // scores/probs bf16 [B][N][N]
  u16* AO  = Xb;                // attention output reuses X's buffer

  // 1. convert X to bf16
  cvt_f32_bf16<<<dim3((unsigned)(SZX / 8 / 256)), 256, 0, stream>>>(X, Xb, (int)(SZX / 8));

  // 2. transpose+convert weights (Bt layout for all GEMMs)
  transpose_cvt<<<dim3(32, 32, 4), dim3(32, 8), 0, stream>>>(Wq, Wk, Wv, Wo, Wqt, Wkt, Wvt, Wot);

  // 3. fused Q,K projection: [16384,2048] = X @ [Wq|Wk] (+ bq|bk)
  gemm256<false, 3><<<dim3(2 * D / 256, TOK / 256, 1), 512, 0, stream>>>(
      Xb, Wqt, QK, bq, bk, (int)TOK, 2 * D, D, D, D, 1.f, 0, 0, 0);

  // 4. Vt[b] = (X[b]@Wv)^T = Wv^T @ X[b]^T  -> [D, N] per batch (row bias = bv)
  gemm256<false, 2><<<dim3(N / 256, D / 256, B), 512, 0, stream>>>(
      Wvt, Xb, Vt, bv, nullptr, D, N, D, D, D, 1.f, 0, (long)N * D, (long)D * N);

  // 5. S[b] = Q[b] @ K[b]^T * 1/32   [N,N] bf16, into d_out
  gemm256<false, 0><<<dim3(N / 256, N / 256, B), 512, 0, stream>>>(
      QK, QK + D, S, nullptr, nullptr, N, N, D, 2 * D, 2 * D, 0.03125f,
      (long)N * 2 * D, (long)N * 2 * D, (long)N * N);

  // 6. row softmax in place
  softmax_rows<<<dim3((unsigned)(B * N)), 256, 0, stream>>>(S);

  // 7. AO[b] = P[b] @ V[b]   (Bt = Vt[b])   [N, D] bf16
  gemm256<false, 0><<<dim3(D / 256, N / 256, B), 512, 0, stream>>>(
      S, Vt, AO, nullptr, nullptr, N, D, N, N, N, 1.f,
      (long)N * N, (long)D * N, (long)N * D);

  // 8. out = AO @ Wo + bo   [16384,1024] fp32 -> d_out (overwrites dead S)
  gemm256<true, 1><<<dim3(D / 256, TOK / 256, 1), 512, 0, stream>>>(
      AO, Wot, d_out, bo, nullptr, (int)TOK, D, D, D, D, 1.f, 0, 0, 0);
}

// Round 4
// 346.120 us; speedup vs baseline: 1.0945x; 1.0945x over previous
//
#include <hip/hip_runtime.h>
#include <hip/hip_bf16.h>
#include <stdint.h>

#define DEVINL __device__ __forceinline__

typedef unsigned short u16;
typedef __attribute__((ext_vector_type(8))) short bf16x8;   // 8 bf16 = 4 VGPRs (MFMA A/B frag)
typedef __attribute__((ext_vector_type(4))) float f32x4;    // MFMA C/D frag
typedef __attribute__((ext_vector_type(8))) unsigned short u16x8;

DEVINL u16 f2bf(float f) {               // round-to-nearest-even f32 -> bf16
  union { float f; unsigned u; } x; x.f = f;
  unsigned r = x.u + 0x7fffu + ((x.u >> 16) & 1u);
  return (u16)(r >> 16);
}
DEVINL float bf2f(u16 u) {
  union { float f; unsigned u; } x; x.u = ((unsigned)u) << 16; return x.f;
}

DEVINL void load_lds16(const u16* g, u16* l) {
  // async global->LDS, 16B per lane; LDS dest = wave-uniform base + lane*16
  __builtin_amdgcn_global_load_lds(
      (const __attribute__((address_space(1))) void*)g,
      (__attribute__((address_space(3))) void*)l, 16, 0, 0);
}

// ---------------------------------------------------------------------------
// C[M,N] = A[M,K] @ Bt[N,K]^T * scale (+ bias)    A,Bt bf16; C bf16 or f32
// A row stride = lda, Bt row stride = ldb, C row stride = N.
// BIAS_MODE: 0 none, 1 bias[col], 2 bias[row], 3 dual col bias split at N/2
// ZSWZ: batch-coherent XCD remap (requires gridDim.z == 8): work_z = lin&7,
//       so all concurrent blocks on one XCD share one batch's panels.
// 256x256 tile, BK=32, ring-4 LDS slots, counted-vmcnt pipeline (depth 3),
// 16x16x32 MFMA (round-2 pattern: HW-verified 0 bank conflicts).
// 512 threads = 8 waves (2M x 4N), wave tile 128x64 -> acc[8][4] of f32x4.
//
// Race-freedom: iteration t reads slot t&3 after {vmcnt(8); s_barrier}:
// vmcnt(8) retires this wave's 4 loads of tile t (tiles t+1,t+2 = 8 loads in
// flight); barrier extends to all waves. stage(t+3) -> slot (t-1)&3, whose
// readers all passed this barrier. One barrier per K-step; never vmcnt(0)
// mid-loop. LDS swizzle: 16B-block blk' = blk ^ ((row>>1)&3) applied on the
// GLOBAL source (global_load_lds writes linearly) and on the ds_read address.
// ---------------------------------------------------------------------------
template<bool OUT_F32, int BIAS_MODE, bool ZSWZ>
__global__ __launch_bounds__(512)
void gemm256(const u16* __restrict__ A, const u16* __restrict__ Bt,
             void* __restrict__ Cv,
             const float* __restrict__ bias, const float* __restrict__ bias2,
             int M, int N, int K, int lda, int ldb, float scale,
             long sA, long sB, long sC)
{
  int bxs = blockIdx.x, bys = blockIdx.y, bz = blockIdx.z;
  if (ZSWZ) {
    const int lin  = blockIdx.x + gridDim.x * (blockIdx.y + gridDim.y * blockIdx.z);
    bz = lin & 7;
    const int rest = lin >> 3;
    bxs = rest % gridDim.x;
    bys = rest / gridDim.x;
  }
  A  += (size_t)bz * sA;
  Bt += (size_t)bz * sB;

  const int tid  = threadIdx.x;
  const int lane = tid & 63;
  const int w    = tid >> 6;
  const int wm   = w >> 2;          // 0..1  (M direction, 128 rows each)
  const int wn   = w & 3;           // 0..3  (N direction, 64 cols each)
  const int brow = bys * 256;
  const int bcol = bxs * 256;

  __shared__ u16 lds[4][2][256 * 32];   // [slot][A/B][row*32+col]  128 KiB

  const u16* gA = A  + (size_t)brow * lda;
  const u16* gB = Bt + (size_t)bcol * ldb;

  // per-thread staging descriptors: 2 rounds x (A,B); 16B chunk c = r*512+tid
  int c8[2], soffA[2], soffB[2];
#pragma unroll
  for (int r = 0; r < 2; ++r) {
    const int c    = r * 512 + tid;
    const int row  = c >> 2;
    const int blk  = c & 3;
    const int sblk = blk ^ ((row >> 1) & 3);   // inverse swizzle on source
    c8[r]    = c * 8;
    soffA[r] = row * lda + sblk * 8;
    soffB[r] = row * ldb + sblk * 8;
  }
  const int NT = K >> 5;

  f32x4 acc[8][4] = {};

  // prologue: stage tiles 0..2
#pragma unroll
  for (int tt = 0; tt < 3; ++tt) {
    const int kt = tt * 32;
#pragma unroll
    for (int r = 0; r < 2; ++r) load_lds16(gA + soffA[r] + kt, &lds[tt][0][c8[r]]);
#pragma unroll
    for (int r = 0; r < 2; ++r) load_lds16(gB + soffB[r] + kt, &lds[tt][1][c8[r]]);
  }
  __builtin_amdgcn_sched_barrier(0);

  // read addressing (HW-verified conflict-free): quarter kq = lane>>4 picks
  // k-block; rsw = (kq ^ ((lane>>1)&3))*8 matches the write-side swizzle.
  const int rsw   = ((lane >> 4) ^ ((lane >> 1) & 3)) * 8;
  const int arow0 = wm * 128 + (lane & 15);
  const int brow0 = wn * 64  + (lane & 15);

  for (int t = 0; t < NT; ++t) {
    if (t < NT - 2)       asm volatile("s_waitcnt vmcnt(8)" ::: "memory");
    else if (t == NT - 2) asm volatile("s_waitcnt vmcnt(4)" ::: "memory");
    else                  asm volatile("s_waitcnt vmcnt(0)" ::: "memory");
    __builtin_amdgcn_s_barrier();
    __builtin_amdgcn_sched_barrier(0);

    const u16* la = lds[t & 3][0];
    const u16* lb = lds[t & 3][1];
    bf16x8 av[8], bv[4];
#pragma unroll
    for (int m = 0; m < 8; ++m)
      av[m] = *(const bf16x8*)&la[(arow0 + m * 16) * 32 + rsw];
#pragma unroll
    for (int n = 0; n < 4; ++n)
      bv[n] = *(const bf16x8*)&lb[(brow0 + n * 16) * 32 + rsw];

    if (t + 3 < NT) {                      // stage tile t+3 into slot (t-1)&3
      const int kt = (t + 3) * 32, sl = (t + 3) & 3;
#pragma unroll
      for (int r = 0; r < 2; ++r) load_lds16(gA + soffA[r] + kt, &lds[sl][0][c8[r]]);
#pragma unroll
      for (int r = 0; r < 2; ++r) load_lds16(gB + soffB[r] + kt, &lds[sl][1][c8[r]]);
    }

    __builtin_amdgcn_s_setprio(1);
#pragma unroll
    for (int m = 0; m < 8; ++m)
#pragma unroll
      for (int n = 0; n < 4; ++n)
        acc[m][n] = __builtin_amdgcn_mfma_f32_16x16x32_bf16(av[m], bv[n], acc[m][n], 0, 0, 0);
    __builtin_amdgcn_s_setprio(0);
  }

  // epilogue: C/D layout col = lane&15, row = (lane>>4)*4 + j  [m89-verified]
  float* Cf = (float*)Cv + (size_t)bz * sC;
  u16*   Cb = (u16*)Cv   + (size_t)bz * sC;
  const int r0base  = brow + wm * 128 + ((lane >> 4) << 2);
  const int colbase = bcol + wn * 64  + (lane & 15);
#pragma unroll
  for (int m = 0; m < 8; ++m) {
    const int r0 = r0base + m * 16;
#pragma unroll
    for (int n = 0; n < 4; ++n) {
      const int col = colbase + n * 16;
      float badd = 0.f;
      if (BIAS_MODE == 1) badd = bias[col];
      if (BIAS_MODE == 3) badd = (col < (N >> 1)) ? bias[col] : bias2[col - (N >> 1)];
#pragma unroll
      for (int j = 0; j < 4; ++j) {
        const int row = r0 + j;
        float v = acc[m][n][j] * scale + badd;
        if (BIAS_MODE == 2) v += bias[row];
        if (OUT_F32) Cf[(size_t)row * N + col] = v;
        else         Cb[(size_t)row * N + col] = f2bf(v);
      }
    }
  }
}

// ---------------------------------------------------------------------------
__global__ __launch_bounds__(256)
void cvt_f32_bf16(const float* __restrict__ in, u16* __restrict__ out, int n8)
{
  const int i = blockIdx.x * 256 + threadIdx.x;
  if (i >= n8) return;
  const float4* in4 = (const float4*)in;
  float4 a = in4[2 * i], b = in4[2 * i + 1];
  u16x8 o;
  o[0] = f2bf(a.x); o[1] = f2bf(a.y); o[2] = f2bf(a.z); o[3] = f2bf(a.w);
  o[4] = f2bf(b.x); o[5] = f2bf(b.y); o[6] = f2bf(b.z); o[7] = f2bf(b.w);
  ((u16x8*)out)[i] = o;
}

// transpose + convert 1024x1024 fp32 -> bf16 (Wt[e][d] = W[d][e]), z picks weight
__global__ __launch_bounds__(256)
void transpose_cvt(const float* __restrict__ W0, const float* __restrict__ W1,
                   const float* __restrict__ W2, const float* __restrict__ W3,
                   u16* __restrict__ T0, u16* __restrict__ T1,
                   u16* __restrict__ T2, u16* __restrict__ T3)
{
  const float* W = blockIdx.z == 0 ? W0 : blockIdx.z == 1 ? W1 : blockIdx.z == 2 ? W2 : W3;
  u16*         T = blockIdx.z == 0 ? T0 : blockIdx.z == 1 ? T1 : blockIdx.z == 2 ? T2 : T3;
  __shared__ float tile[32][33];
  const int d0 = blockIdx.y * 32, e0 = blockIdx.x * 32;
  const int tx = threadIdx.x, ty = threadIdx.y;
#pragma unroll
  for (int r = ty; r < 32; r += 8)
    tile[r][tx] = W[(size_t)(d0 + r) * 1024 + e0 + tx];
  __syncthreads();
#pragma unroll
  for (int r = ty; r < 32; r += 8)
    T[(size_t)(e0 + r) * 1024 + d0 + tx] = f2bf(tile[tx][r]);
}

// row softmax in place over bf16 rows of length 2048 (one block per row)
__global__ __launch_bounds__(256)
void softmax_rows(u16* __restrict__ S)
{
  u16* p = S + (size_t)blockIdx.x * 2048;
  const int tid = threadIdx.x;
  const int w = tid >> 6, lane = tid & 63;

  u16x8 v = ((const u16x8*)p)[tid];
  float f[8];
  float m = -1e30f;
#pragma unroll
  for (int j = 0; j < 8; ++j) { f[j] = bf2f(v[j]); m = fmaxf(m, f[j]); }
#pragma unroll
  for (int o = 32; o; o >>= 1) m = fmaxf(m, __shfl_xor(m, o));

  __shared__ float red[8];
  if (lane == 0) red[w] = m;
  __syncthreads();
  m = fmaxf(fmaxf(red[0], red[1]), fmaxf(red[2], red[3]));

  float s = 0.f;
#pragma unroll
  for (int j = 0; j < 8; ++j) { f[j] = __expf(f[j] - m); s += f[j]; }
#pragma unroll
  for (int o = 32; o; o >>= 1) s += __shfl_xor(s, o);
  if (lane == 0) red[4 + w] = s;
  __syncthreads();
  s = red[4] + red[5] + red[6] + red[7];
  const float inv = 1.f / s;

  u16x8 o8;
#pragma unroll
  for (int j = 0; j < 8; ++j) o8[j] = f2bf(f[j] * inv);
  ((u16x8*)p)[tid] = o8;
}

// ---------------------------------------------------------------------------
extern "C" void kernel_launch(void* const* d_in, const int* in_sizes, int n_in,
                              void* d_out, int out_size, void* d_ws, size_t ws_size,
                              hipStream_t stream)
{
  const float* X  = (const float*)d_in[0];
  const float* Wq = (const float*)d_in[1];
  const float* bq = (const float*)d_in[2];
  const float* Wk = (const float*)d_in[3];
  const float* bk = (const float*)d_in[4];
  const float* Wv = (const float*)d_in[5];
  const float* bv = (const float*)d_in[6];
  const float* Wo = (const float*)d_in[7];
  const float* bo = (const float*)d_in[8];

  constexpr int B = 8, N = 2048, D = 1024;
  constexpr size_t TOK = (size_t)B * N;        // 16384
  constexpr size_t SZX = TOK * D;              // 16,777,216 elems
  constexpr size_t SZW = (size_t)D * D;

  if (ws_size < (4 * SZX + 4 * SZW) * sizeof(u16)) return;  // ~143 MB needed

  u16* Xb  = (u16*)d_ws;        // X bf16; later reused as attn_out (AO)
  u16* Wqt = Xb  + SZX;         // Wq^T  — Wqt/Wkt contiguous => stacked QK weight
  u16* Wkt = Wqt + SZW;
  u16* Wvt = Wkt + SZW;
  u16* Wot = Wvt + SZW;
  u16* QK  = Wot + SZW;         // fused [16384][2048]: cols 0..1023 Q, 1024..2047 K
  u16* Vt  = QK  + 2 * SZX;     // [B][D][N] (V transposed per batch)
  u16* S   = (u16*)d_out;       // scores/probs bf16 [B][N][N]
  u16* AO  = Xb;                // attention output reuses X's buffer

  // 1. convert X to bf16
  cvt_f32_bf16<<<dim3((unsigned)(SZX / 8 / 256)), 256, 0, stream>>>(X, Xb, (int)(SZX / 8));

  // 2. transpose+convert weights (Bt layout for all GEMMs)
  transpose_cvt<<<dim3(32, 32, 4), dim3(32, 8), 0, stream>>>(Wq, Wk, Wv, Wo, Wqt, Wkt, Wvt, Wot);

  // 3. fused Q,K projection: [16384,2048] = X @ [Wq|Wk] (+ bq|bk)
  gemm256<false, 3, false><<<dim3(2 * D / 256, TOK / 256, 1), 512, 0, stream>>>(
      Xb, Wqt, QK, bq, bk, (int)TOK, 2 * D, D, D, D, 1.f, 0, 0, 0);

  // 4. Vt[b] = (X[b]@Wv)^T = Wv^T @ X[b]^T  -> [D, N] per batch (row bias = bv)
  gemm256<false, 2, true><<<dim3(N / 256, D / 256, B), 512, 0, stream>>>(
      Wvt, Xb, Vt, bv, nullptr, D, N, D, D, D, 1.f, 0, (long)N * D, (long)D * N);

  // 5. S[b] = Q[b] @ K[b]^T * 1/32   [N,N] bf16, into d_out
  gemm256<false, 0, true><<<dim3(N / 256, N / 256, B), 512, 0, stream>>>(
      QK, QK + D, S, nullptr, nullptr, N, N, D, 2 * D, 2 * D, 0.03125f,
      (long)N * 2 * D, (long)N * 2 * D, (long)N * N);

  // 6. row softmax in place
  softmax_rows<<<dim3((unsigned)(B * N)), 256, 0, stream>>>(S);

  // 7. AO[b] = P[b] @ V[b]   (Bt = Vt[b])   [N, D] bf16
  gemm256<false, 0, true><<<dim3(D / 256, N / 256, B), 512, 0, stream>>>(
      S, Vt, AO, nullptr, nullptr, N, D, N, N, N, 1.f,
      (long)N * N, (long)D * N, (long)N * D);

  // 8. out = AO @ Wo + bo   [16384,1024] fp32 -> d_out (overwrites dead S)
  gemm256<true, 1, false><<<dim3(D / 256, TOK / 256, 1), 512, 0, stream>>>(
      AO, Wot, d_out, bo, nullptr, (int)TOK, D, D, D, D, 1.f, 0, 0, 0);
}